// Round 22
// baseline (859.466 us; speedup 1.0000x reference)
//
#include <hip/hip_runtime.h>
#include <math.h>

typedef unsigned int u32;
typedef unsigned long long u64;
typedef unsigned short u16;

#define STRIDE 262656          // per-column stride in ELEMENTS
#define KSHIFT 15
#define KROUND 0x4000u
#define BAND   6144            // 24 exponents x 256 mantissa steps per sign
#define NB     12288           // bins per column
#define PA17   0x7100u
#define NA17   0x17700u
#define NCOLS  16
#define ZW     (NB*NCOLS)      // u32 words in one bin buffer
#define ACT_PRELU 0
#define ACT_RELU  1
#define ACT_ELU   2

// LDS pad-swizzle for conv9: logical i -> physical i + i/32
#define SW(i) ((i) + ((i) >> 5))

__device__ __forceinline__ float k2f(u32 k){
    u32 u = (k & 0x80000000u) ? k : (k ^ 0x7FFFFFFFu);
    return __uint_as_float(u);
}
__device__ __forceinline__ int bin_of(float v){
    float av = fabsf(v);
    av = fminf(fmaxf(av, 0.00390625f), 65535.96875f);
    u32 u = __float_as_uint(av);
    if (v < 0.f){
        u32 k = 0x80000000u | u;
        int b = (int)(((k + KROUND) >> KSHIFT) - NA17);
        b = b < 0 ? 0 : (b > BAND-1 ? BAND-1 : b);
        return BAND + b;
    } else {
        u32 k = u ^ 0x7FFFFFFFu;
        int b = (int)(((k + KROUND) >> KSHIFT) - PA17);
        b = b < 0 ? 0 : (b > BAND-1 ? BAND-1 : b);
        return b;
    }
}
__device__ __forceinline__ float bin_val(int bin){
    u32 k17 = (bin < BAND) ? ((u32)bin + PA17) : ((u32)(bin - BAND) + NA17);
    return k2f(k17 << KSHIFT);
}
__device__ __forceinline__ float act_apply(int act, float alpha, float v){
    if (act == ACT_PRELU) return (v >= 0.f) ? v : alpha * v;
    if (act == ACT_RELU)  return (v > 0.f) ? v : 0.f;
    return (v > 0.f) ? v : expm1f(v);
}
// decode u16 bin index -> activated float (exactly what the float path stored)
__device__ __forceinline__ float dec(u16 idx, int act, float alpha){
    return act_apply(act, alpha, bin_val((int)idx));
}

// wave run-length dedup -> one GLOBAL atomic per run per wave
__device__ __forceinline__ void hist_add(u32* __restrict__ Hc, int bin, bool valid, int lane){
    u32 bn = valid ? (u32)bin : 0xFFFFFFFFu;
    u32 prev = __shfl_up(bn, 1);
    bool diff = (lane == 0) || (prev != bn);
    u64 m = __ballot(diff || !valid);
    if (valid && diff){
        u64 above = m & ~((2ull << lane) - 1ull);
        int nxt = above ? (__ffsll((unsigned long long)above) - 1) : 64;
        atomicAdd(&Hc[bin], (u32)(nxt - lane));
    }
}

// wave run-length dedup -> one packed-u16 LDS atomic per run per wave
__device__ __forceinline__ void lds_hist_dedup(u32* __restrict__ hist, int bin, bool valid, int lane){
    u32 bn = valid ? (u32)bin : 0xFFFFFFFFu;
    u32 prev = __shfl_up(bn, 1);
    bool diff = (lane == 0) || (prev != bn);
    u64 m = __ballot(diff || !valid);
    if (valid && diff){
        u64 above = m & ~((2ull << lane) - 1ull);
        int nxt = above ? (__ffsll((unsigned long long)above) - 1) : 64;
        u32 cnt = (u32)(nxt - lane);
        atomicAdd(&hist[bin >> 1], cnt << ((bin & 1) * 16));
    }
}

// ---------------- fold+transpose x -> fx[8][STRIDE]; also zero bin0 ----------------
__global__ __launch_bounds__(256) void foldx(const float* __restrict__ x, float* __restrict__ fx,
                                             uint4* __restrict__ zb)
{
    __shared__ float4 tile[1024];    // 256 rows x 16 floats
    const int tid = threadIdx.x;
    const int h0 = blockIdx.x * 256;
    for (int i = tid; i < 1024; i += 256) tile[i] = ((const float4*)x)[(size_t)h0*4 + i];
    __syncthreads();
    float4 a = tile[tid*4+0], b = tile[tid*4+1], c = tile[tid*4+2], d = tile[tid*4+3];
    const int h = h0 + tid;
    fx[(size_t)0*STRIDE + h] = a.x + a.y;
    fx[(size_t)1*STRIDE + h] = a.z + a.w;
    fx[(size_t)2*STRIDE + h] = b.x + b.y;
    fx[(size_t)3*STRIDE + h] = b.z + b.w;
    fx[(size_t)4*STRIDE + h] = c.x + c.y;
    fx[(size_t)5*STRIDE + h] = c.z + c.w;
    fx[(size_t)6*STRIDE + h] = d.x + d.y;
    fx[(size_t)7*STRIDE + h] = d.z + d.w;
    const uint4 z = make_uint4(0,0,0,0);
    for (int i = blockIdx.x*256 + tid; i < ZW/4; i += gridDim.x*256) zb[i] = z;
}

// ---------------- layer-0 conv+hist: float4 shifted window, 4 outputs/thread ----------------
#define C0CHUNK 8192             // 4 tiles of 2048; 33 chunks x 16 cols = 528 blocks (~2/CU)
__global__ __launch_bounds__(512) void conv0_lds(const float* __restrict__ fx, u32* __restrict__ H,
                                                 const float* __restrict__ w0, const float* __restrict__ b0)
{
    __shared__ u32 hist[NB/2];                 // 24 KB packed u16 pairs
    __shared__ __align__(16) float s0f[2148];  // window floats [t0-98, t0+2049]; 537 float4s
    __shared__ float sw[100];                  // sw[99] = 0 pad
    const int colv = blockIdx.y;               // 0..15 = o*8 + wp
    const int o = colv >> 3, wp = colv & 7;
    const int tid = threadIdx.x;
    const int p0 = blockIdx.x * C0CHUNK;
    const int p1 = min(p0 + C0CHUNK, 262242);
    if (p0 >= 262242) return;
    for (int i = tid; i < NB/2; i += 512) hist[i] = 0;
    if (tid < 99) sw[tid] = w0[o*99 + tid];
    if (tid == 99) sw[99] = 0.f;
    const float bias = 2.f * b0[o];            // fold doubles bias
    __syncthreads();
    const float* fc = fx + (size_t)wp * STRIDE;
    const float4* s4 = (const float4*)s0f;
    for (int t0 = p0; t0 < p1; t0 += 2048){
        for (int i = tid; i < 2148; i += 512){
            int h = t0 - 98 + i;
            s0f[i] = (h >= 0 && h < 262144) ? fc[h] : 0.f;
        }
        __syncthreads();
        float a0 = bias, a1 = bias, a2 = bias, a3 = bias;
        float4 c = s4[tid];
        #pragma unroll
        for (int jb = 0; jb < 25; jb++){
            float4 n = s4[tid + jb + 1];
            float w0_ = sw[4*jb+0], w1_ = sw[4*jb+1], w2_ = sw[4*jb+2], w3_ = sw[4*jb+3];
            a0 += w0_*c.x; a1 += w0_*c.y; a2 += w0_*c.z; a3 += w0_*c.w;
            a0 += w1_*c.y; a1 += w1_*c.z; a2 += w1_*c.w; a3 += w1_*n.x;
            a0 += w2_*c.z; a1 += w2_*c.w; a2 += w2_*n.x; a3 += w2_*n.y;
            a0 += w3_*c.w; a1 += w3_*n.x; a2 += w3_*n.y; a3 += w3_*n.z;   // sw[99]=0
            c = n;
        }
        int hp = t0 + tid*4;
        if (hp     < p1){ int b = bin_of(a0); atomicAdd(&hist[b>>1], 1u << ((b&1)*16)); }
        if (hp + 1 < p1){ int b = bin_of(a1); atomicAdd(&hist[b>>1], 1u << ((b&1)*16)); }
        if (hp + 2 < p1){ int b = bin_of(a2); atomicAdd(&hist[b>>1], 1u << ((b&1)*16)); }
        if (hp + 3 < p1){ int b = bin_of(a3); atomicAdd(&hist[b>>1], 1u << ((b&1)*16)); }
        __syncthreads();
    }
    u32* Hc = H + (size_t)colv * NB;
    for (int i = tid; i < NB/2; i += 512){
        u32 w = hist[i];
        if (w){
            u32 lo = w & 0xFFFFu, hi = w >> 16;
            if (lo) atomicAdd(&Hc[2*i],   lo);
            if (hi) atomicAdd(&Hc[2*i+1], hi);
        }
    }
}

// ---------------- K=9 conv+hist: u16-bin input, 2 outputs/thread, swizzled LDS ----------------
#define C9CHUNK 8192
template<int FOLDIN>
__global__ __launch_bounds__(512) void conv9_lds(
    const u16* __restrict__ In, u32* __restrict__ H,
    const float* __restrict__ Wt, const float* __restrict__ Bs,
    int Hin, int Hout, int Wi, int Wo, float bscale,
    int prevAct, const float* __restrict__ prevAlpha)
{
    __shared__ u32 hist[NB/2];       // 24 KB
    __shared__ float s0[1065];       // swizzled 1032 logical
    __shared__ float s1[1065];
    __shared__ float sw[18];
    const int colv = blockIdx.y;     // o*Wo + wp
    const int o = colv / Wo, wp = colv % Wo;
    const int tid = threadIdx.x;
    const int lane = tid & 63;
    const int p0 = blockIdx.x * C9CHUNK;
    const int p1 = min(p0 + C9CHUNK, Hout);
    if (p0 >= Hout) return;
    for (int i = tid; i < NB/2; i += 512) hist[i] = 0;
    if (tid < 18) sw[tid] = Wt[(o*2)*9 + tid];
    const float bv = bscale * Bs[o];
    const float pal = prevAlpha[0];
    __syncthreads();
    const u16* i00 = In + (size_t)(0*Wi + (FOLDIN ? 2*wp   : wp))*STRIDE;
    const u16* i01 = In + (size_t)(0*Wi + (FOLDIN ? 2*wp+1 : wp))*STRIDE;
    const u16* i10 = In + (size_t)(1*Wi + (FOLDIN ? 2*wp   : wp))*STRIDE;
    const u16* i11 = In + (size_t)(1*Wi + (FOLDIN ? 2*wp+1 : wp))*STRIDE;
    for (int t0 = p0; t0 < p1; t0 += 1024){
        for (int i = tid; i < 1032; i += 512){
            int h = t0 - 8 + i;
            float v0 = 0.f, v1 = 0.f;
            if (h >= 0 && h < Hin){
                if (FOLDIN){
                    v0 = dec(i00[h], prevAct, pal) + dec(i01[h], prevAct, pal);
                    v1 = dec(i10[h], prevAct, pal) + dec(i11[h], prevAct, pal);
                } else {
                    v0 = dec(i00[h], prevAct, pal);
                    v1 = dec(i10[h], prevAct, pal);
                }
            }
            s0[SW(i)] = v0; s1[SW(i)] = v1;
        }
        __syncthreads();
        const int base = tid * 2;
        float a0 = bv, a1 = bv;
        {   // channel 0 first (preserve original accumulation order)
            float x0 = s0[SW(base)];
            #pragma unroll
            for (int j = 0; j < 9; j++){
                float x1 = s0[SW(base + j + 1)];
                a0 += sw[j] * x0;
                a1 += sw[j] * x1;
                x0 = x1;
            }
        }
        {   // then channel 1
            float x0 = s1[SW(base)];
            #pragma unroll
            for (int j = 0; j < 9; j++){
                float x1 = s1[SW(base + j + 1)];
                a0 += sw[9 + j] * x0;
                a1 += sw[9 + j] * x1;
                x0 = x1;
            }
        }
        int hp = t0 + base;
        lds_hist_dedup(hist, bin_of(a0), hp     < p1, lane);
        lds_hist_dedup(hist, bin_of(a1), hp + 1 < p1, lane);
        __syncthreads();
    }
    u32* Hc = H + (size_t)colv * NB;
    for (int i = tid; i < NB/2; i += 512){
        u32 w = hist[i];
        if (w){
            u32 lo = w & 0xFFFFu, hi = w >> 16;
            if (lo) atomicAdd(&Hc[2*i],   lo);
            if (hi) atomicAdd(&Hc[2*i+1], hi);
        }
    }
}

// ---------------- layer-19 conv+hist (K=358, 2->5ch; u16-bin input; global dedup atomics) ----------------
template<int INC, int OUTC>
__global__ __launch_bounds__(256) void conv_hist_t(
    const u16* __restrict__ In, u32* __restrict__ H,
    const float* __restrict__ Wt, const float* __restrict__ Bs,
    int Hin, int Hout, int K, int pad, int Wi, int Wo, int foldIn, float bscale,
    int prevAct, const float* __restrict__ prevAlpha)
{
    __shared__ float sIn[INC][613];
    __shared__ float sW[OUTC*INC*358];
    const int wp = blockIdx.y;
    const int h0 = blockIdx.x * 256;
    const int tid = threadIdx.x;
    const int lane = tid & 63;
    const int tl = 256 + K - 1;
    const float pal = prevAlpha[0];
    for (int t = tid; t < INC*tl; t += 256){
        int c = t / tl, r = t - c*tl;
        int h = h0 - pad + r;
        float v = 0.f;
        if (h >= 0 && h < Hin){
            if (foldIn) v = dec(In[(size_t)(c*Wi + 2*wp)*STRIDE + h], prevAct, pal)
                          + dec(In[(size_t)(c*Wi + 2*wp + 1)*STRIDE + h], prevAct, pal);
            else        v = dec(In[(size_t)(c*Wi + wp)*STRIDE + h], prevAct, pal);
        }
        sIn[c][r] = v;
    }
    for (int t = tid; t < OUTC*INC*K; t += 256) sW[t] = Wt[t];
    __syncthreads();
    int hp = h0 + tid;
    bool valid = (hp < Hout);
    float acc[OUTC];
    #pragma unroll
    for (int o = 0; o < OUTC; o++) acc[o] = bscale * Bs[o];
    for (int c = 0; c < INC; c++){
        for (int j = 0; j < K; j++){
            float xv = sIn[c][tid + j];
            #pragma unroll
            for (int o = 0; o < OUTC; o++) acc[o] += sW[(o*INC + c)*K + j] * xv;
        }
    }
    #pragma unroll
    for (int o = 0; o < OUTC; o++)
        hist_add(H + (size_t)(o*Wo + wp)*NB, bin_of(acc[o]), valid, lane);
}

// ---------------- fused scan + reconstruct + next-bin zeroing ----------------
// asBin=1: write u16 bin indices (activation deferred to the reader); asBin=0: write activated floats.
__global__ __launch_bounds__(1024) void scan_fill(
    const u32* __restrict__ H, void* __restrict__ dst, const float* __restrict__ alphaPtr,
    int kOut, int dup, int act, int asBin, uint4* __restrict__ zb)
{
    __shared__ u32 pre[NB];          // 48 KB inclusive prefix
    __shared__ u32 warr[16];
    const int col = blockIdx.y;
    const int tid = threadIdx.x;
    const int lane = tid & 63, wv = tid >> 6;
    const u32* Hc = H + (size_t)col * NB;
    for (int i = tid; i < NB; i += 1024) pre[i] = Hc[i];
    __syncthreads();
    const int base = tid * 12;
    u32 v[12]; u32 s = 0;
    #pragma unroll
    for (int i = 0; i < 12; i++){ v[i] = pre[base + i]; s += v[i]; v[i] = s; }
    u32 ss = s;
    #pragma unroll
    for (int d = 1; d < 64; d <<= 1){
        u32 t = __shfl_up(ss, d);
        if (lane >= d) ss += t;
    }
    if (lane == 63) warr[wv] = ss;
    __syncthreads();
    u32 wb = 0;
    #pragma unroll
    for (int w = 0; w < 16; w++) wb += (w < wv) ? warr[w] : 0u;
    u32 excl = wb + ss - s;
    #pragma unroll
    for (int i = 0; i < 12; i++) pre[base + i] = v[i] + excl;
    __syncthreads();

    const int S  = gridDim.x;
    const int nr = kOut / dup;
    const int per = (nr + S*1024 - 1) / (S*1024);
    int i = (blockIdx.x*1024 + tid) * per;
    const int i1 = min(i + per, nr);
    const float alpha = alphaPtr[0];
    int lo0 = 0;                                  // monotone lower bound across runs
    if (asBin){
        u16* d16 = (u16*)dst + (size_t)col * STRIDE;
        while (i < i1){
            int lo = lo0, hi = NB - 1;
            while (lo < hi){ int m = (lo + hi) >> 1; if (pre[m] > (u32)i) hi = m; else lo = m + 1; }
            u16 bv = (u16)lo;
            int e = (int)min((u32)i1, pre[lo]);
            for (; i < e; i++){
                int bse = i * dup;
                for (int dd = 0; dd < dup; dd++) d16[bse + dd] = bv;
            }
            lo0 = lo + 1;
        }
    } else {
        float* d = (float*)dst + (size_t)col * STRIDE;
        while (i < i1){
            int lo = lo0, hi = NB - 1;
            while (lo < hi){ int m = (lo + hi) >> 1; if (pre[m] > (u32)i) hi = m; else lo = m + 1; }
            float vv = bin_val(lo);
            if (act == ACT_PRELU)      vv = (vv >= 0.f) ? vv : alpha * vv;
            else if (act == ACT_RELU)  vv = (vv > 0.f) ? vv : 0.f;
            else                       vv = (vv > 0.f) ? vv : expm1f(vv);
            int e = (int)min((u32)i1, pre[lo]);
            for (; i < e; i++){
                int bse = i * dup;
                for (int dd = 0; dd < dup; dd++) d[bse + dd] = vv;
            }
            lo0 = lo + 1;
        }
    }
    // zero the other bin buffer for the next layer (vectorized)
    const uint4 z = make_uint4(0,0,0,0);
    int lin = (blockIdx.y * gridDim.x + blockIdx.x) * 1024 + tid;
    int tot = gridDim.x * gridDim.y * 1024;
    for (int q = lin; q < ZW/4; q += tot) zb[q] = z;
}

// ---------------- FC: 1000 logits, one block each; then log_softmax ----------------
__global__ __launch_bounds__(256) void fc_dot(const float* __restrict__ A, const float* __restrict__ Wfc,
                                              const float* __restrict__ bfc, float* __restrict__ logits)
{
    const int t = blockIdx.x;            // 0..999
    const int o = t / 200, j = t - o*200;
    const float* wrow = Wfc + (size_t)j*1600;
    float acc = 0.f;
    for (int q = threadIdx.x; q < 1600; q += 256){
        int p = q >> 1, wq = q & 1;
        acc += wrow[q] * A[(size_t)(o*2 + wq)*STRIDE + p];
    }
    __shared__ float red[256];
    red[threadIdx.x] = acc;
    __syncthreads();
    for (int s = 128; s > 0; s >>= 1){
        if (threadIdx.x < s) red[threadIdx.x] += red[threadIdx.x + s];
        __syncthreads();
    }
    if (threadIdx.x == 0) logits[t] = red[0] + bfc[j];
}

__global__ __launch_bounds__(1024) void lsm(const float* __restrict__ logits, float* __restrict__ out)
{
    const int tid = threadIdx.x;
    __shared__ float red[1024];
    float lg = (tid < 1000) ? logits[tid] : -INFINITY;
    red[tid] = lg;
    __syncthreads();
    for (int s = 512; s > 0; s >>= 1){
        if (tid < s) red[tid] = fmaxf(red[tid], red[tid + s]);
        __syncthreads();
    }
    float m = red[0];
    __syncthreads();
    red[tid] = (tid < 1000) ? expf(lg - m) : 0.f;
    __syncthreads();
    for (int s = 512; s > 0; s >>= 1){
        if (tid < s) red[tid] += red[tid + s];
        __syncthreads();
    }
    float lse = logf(red[0]);
    if (tid < 1000) out[tid] = lg - m - lse;
}

extern "C" void kernel_launch(void* const* d_in, const int* in_sizes, int n_in,
                              void* d_out, int out_size, void* d_ws, size_t ws_size,
                              hipStream_t stream)
{
    (void)in_sizes; (void)n_in; (void)out_size;
    const size_t need = (size_t)24*STRIDE*4 + (size_t)2*ZW*4 + 4096;
    if (ws_size < need) return;

    const float* x   = (const float*)d_in[0];
    const float* w0  = (const float*)d_in[1];
    const float* b0  = (const float*)d_in[2];
    const float* wm  = (const float*)d_in[3];
    const float* bm  = (const float*)d_in[4];
    const float* w18 = (const float*)d_in[5];
    const float* b18 = (const float*)d_in[6];
    const float* w19 = (const float*)d_in[7];
    const float* b19 = (const float*)d_in[8];
    const float* a1  = (const float*)d_in[9];
    const float* a2  = (const float*)d_in[10];
    const float* Wfc = (const float*)d_in[11];
    const float* bfc = (const float*)d_in[12];

    float* b1   = (float*)d_ws;           // layers 0-18: u16 bins; layer 19: floats
    u16*  b1u   = (u16*)d_ws;
    float* fx   = b1 + (size_t)16*STRIDE;
    u32*  bin0  = (u32*)(fx + (size_t)8*STRIDE);
    u32*  bin1  = bin0 + (size_t)ZW;
    float* logits = (float*)(bin1 + (size_t)ZW);

    u32* cur = bin0;
    u32* nxt = bin1;

    // fold+transpose x; zero bin0
    foldx<<<1024, 256, 0, stream>>>(x, fx, (uint4*)cur);

    // ---- layer 0: conv(99, pad 98) -> fold(x2 dup) -> kmax 262144 -> PReLU(a1) ----
    conv0_lds<<<dim3(33, 16), 512, 0, stream>>>(fx, cur, w0, b0);
    scan_fill<<<dim3(16, 16), 1024, 0, stream>>>(cur, b1u, a1, 262144, 2, ACT_PRELU, 1, (uint4*)nxt);
    { u32* t = cur; cur = nxt; nxt = t; }
    int Hin = 262144;

    // ---- layers 1..17: conv(9, pad 8) -> kmax -> PReLU(a2)/ReLU ----
    static const int ks[17] = {249036,235929,222822,209715,196608,183500,170393,157286,
                               144179,131072,117964,104857,91750,78643,65536,52428,39321};
    for (int i = 0; i < 17; i++){
        int Hout = Hin + 8;
        int nch = (Hout + C9CHUNK - 1) / C9CHUNK;
        // previous layer's activation: L0 -> PReLU(a1); L1 -> PReLU(a2); L>=2 -> ReLU
        int pact = (i == 0) ? ACT_PRELU : (i == 1) ? ACT_PRELU : ACT_RELU;
        const float* palpha = (i == 0) ? a1 : a2;
        conv9_lds<0><<<dim3(nch, 16), 512, 0, stream>>>(
            b1u, cur, wm + (size_t)i*36, bm + (size_t)i*2, Hin, Hout, 8, 8, 1.f, pact, palpha);
        scan_fill<<<dim3(16, 16), 1024, 0, stream>>>(cur, b1u, a2, ks[i], 1,
                                                     (i == 0) ? ACT_PRELU : ACT_RELU, 1, (uint4*)nxt);
        { u32* t = cur; cur = nxt; nxt = t; }
        Hin = ks[i];
    }

    // ---- layer 18: conv(9) -> fold(widths 8->4, x2 dup) -> kmax 26214 -> ELU ----
    {
        int Hout = Hin + 8;   // 39329
        int nch = (Hout + C9CHUNK - 1) / C9CHUNK;
        conv9_lds<1><<<dim3(nch, 8), 512, 0, stream>>>(
            b1u, cur, w18, b18, Hin, Hout, 8, 4, 2.f, ACT_RELU, a2);   // L17 output = ReLU
        scan_fill<<<dim3(4, 8), 1024, 0, stream>>>(cur, b1u, a2, 26214, 2, ACT_ELU, 1, (uint4*)nxt);
        { u32* t = cur; cur = nxt; nxt = t; }
        Hin = 26214;
    }

    // ---- layer 19: conv(358, pad 357, 2->5ch) -> fold(widths 4->2, x5 dup) -> kmax 800 -> ELU ----
    {
        int Hout = Hin + 714 - 358 + 1;   // 26571
        conv_hist_t<2,5><<<dim3((Hout + 255)/256, 2), 256, 0, stream>>>(
            b1u, cur, w19, b19, Hin, Hout, 358, 357, 4, 2, 1, 2.f, ACT_ELU, a2);  // L18 output = ELU
        scan_fill<<<dim3(1, 10), 1024, 0, stream>>>(cur, b1, a2, 800, 5, ACT_ELU, 0, (uint4*)nxt);
    }

    // ---- FC + log_softmax ----
    fc_dot<<<1000, 256, 0, stream>>>(b1, Wfc, bfc, logits);
    lsm<<<1, 1024, 0, stream>>>(logits, (float*)d_out);
}

// Round 23
// 727.482 us; speedup vs baseline: 1.1814x; 1.1814x over previous
//
#include <hip/hip_runtime.h>
#include <math.h>

typedef unsigned int u32;
typedef unsigned long long u64;

#define STRIDE 262656          // per-column stride in floats
#define KSHIFT 15
#define KROUND 0x4000u
#define BAND   6144            // 24 exponents x 256 mantissa steps per sign
#define NB     12288           // bins per column
#define PA17   0x7100u
#define NA17   0x17700u
#define NCOLS  16
#define ZW     (NB*NCOLS)      // u32 words in one bin buffer
#define ACT_PRELU 0
#define ACT_RELU  1
#define ACT_ELU   2

__device__ __forceinline__ float k2f(u32 k){
    u32 u = (k & 0x80000000u) ? k : (k ^ 0x7FFFFFFFu);
    return __uint_as_float(u);
}
__device__ __forceinline__ int bin_of(float v){
    float av = fabsf(v);
    av = fminf(fmaxf(av, 0.00390625f), 65535.96875f);
    u32 u = __float_as_uint(av);
    if (v < 0.f){
        u32 k = 0x80000000u | u;
        int b = (int)(((k + KROUND) >> KSHIFT) - NA17);
        b = b < 0 ? 0 : (b > BAND-1 ? BAND-1 : b);
        return BAND + b;
    } else {
        u32 k = u ^ 0x7FFFFFFFu;
        int b = (int)(((k + KROUND) >> KSHIFT) - PA17);
        b = b < 0 ? 0 : (b > BAND-1 ? BAND-1 : b);
        return b;
    }
}
__device__ __forceinline__ float bin_val(int bin){
    u32 k17 = (bin < BAND) ? ((u32)bin + PA17) : ((u32)(bin - BAND) + NA17);
    return k2f(k17 << KSHIFT);
}

// wave run-length dedup -> one GLOBAL atomic per run per wave
__device__ __forceinline__ void hist_add(u32* __restrict__ Hc, int bin, bool valid, int lane){
    u32 bn = valid ? (u32)bin : 0xFFFFFFFFu;
    u32 prev = __shfl_up(bn, 1);
    bool diff = (lane == 0) || (prev != bn);
    u64 m = __ballot(diff || !valid);
    if (valid && diff){
        u64 above = m & ~((2ull << lane) - 1ull);
        int nxt = above ? (__ffsll((unsigned long long)above) - 1) : 64;
        atomicAdd(&Hc[bin], (u32)(nxt - lane));
    }
}

// wave run-length dedup -> one packed-u16 LDS atomic per run per wave
__device__ __forceinline__ void lds_hist_dedup(u32* __restrict__ hist, int bin, bool valid, int lane){
    u32 bn = valid ? (u32)bin : 0xFFFFFFFFu;
    u32 prev = __shfl_up(bn, 1);
    bool diff = (lane == 0) || (prev != bn);
    u64 m = __ballot(diff || !valid);
    if (valid && diff){
        u64 above = m & ~((2ull << lane) - 1ull);
        int nxt = above ? (__ffsll((unsigned long long)above) - 1) : 64;
        u32 cnt = (u32)(nxt - lane);
        atomicAdd(&hist[bin >> 1], cnt << ((bin & 1) * 16));
    }
}

// ---------------- fold+transpose x -> fx[8][STRIDE]; also zero bin0 ----------------
__global__ __launch_bounds__(256) void foldx(const float* __restrict__ x, float* __restrict__ fx,
                                             uint4* __restrict__ zb)
{
    __shared__ float4 tile[1024];    // 256 rows x 16 floats
    const int tid = threadIdx.x;
    const int h0 = blockIdx.x * 256;
    for (int i = tid; i < 1024; i += 256) tile[i] = ((const float4*)x)[(size_t)h0*4 + i];
    __syncthreads();
    float4 a = tile[tid*4+0], b = tile[tid*4+1], c = tile[tid*4+2], d = tile[tid*4+3];
    const int h = h0 + tid;
    fx[(size_t)0*STRIDE + h] = a.x + a.y;
    fx[(size_t)1*STRIDE + h] = a.z + a.w;
    fx[(size_t)2*STRIDE + h] = b.x + b.y;
    fx[(size_t)3*STRIDE + h] = b.z + b.w;
    fx[(size_t)4*STRIDE + h] = c.x + c.y;
    fx[(size_t)5*STRIDE + h] = c.z + c.w;
    fx[(size_t)6*STRIDE + h] = d.x + d.y;
    fx[(size_t)7*STRIDE + h] = d.z + d.w;
    const uint4 z = make_uint4(0,0,0,0);
    for (int i = blockIdx.x*256 + tid; i < ZW/4; i += gridDim.x*256) zb[i] = z;
}

// ---------------- layer-0 conv+hist: float4 shifted window, 4 outputs/thread ----------------
#define C0CHUNK 8192             // 4 tiles of 2048; 33 chunks x 16 cols = 528 blocks (~2/CU)
__global__ __launch_bounds__(512) void conv0_lds(const float* __restrict__ fx, u32* __restrict__ H,
                                                 const float* __restrict__ w0, const float* __restrict__ b0)
{
    __shared__ u32 hist[NB/2];                 // 24 KB packed u16 pairs
    __shared__ __align__(16) float s0f[2148];  // window floats [t0-98, t0+2049]; 537 float4s
    __shared__ float sw[100];                  // sw[99] = 0 pad
    const int colv = blockIdx.y;               // 0..15 = o*8 + wp
    const int o = colv >> 3, wp = colv & 7;
    const int tid = threadIdx.x;
    const int p0 = blockIdx.x * C0CHUNK;
    const int p1 = min(p0 + C0CHUNK, 262242);
    if (p0 >= 262242) return;
    for (int i = tid; i < NB/2; i += 512) hist[i] = 0;
    if (tid < 99) sw[tid] = w0[o*99 + tid];
    if (tid == 99) sw[99] = 0.f;
    const float bias = 2.f * b0[o];            // fold doubles bias
    __syncthreads();
    const float* fc = fx + (size_t)wp * STRIDE;
    const float4* s4 = (const float4*)s0f;
    for (int t0 = p0; t0 < p1; t0 += 2048){
        for (int i = tid; i < 2148; i += 512){
            int h = t0 - 98 + i;
            s0f[i] = (h >= 0 && h < 262144) ? fc[h] : 0.f;
        }
        __syncthreads();
        float a0 = bias, a1 = bias, a2 = bias, a3 = bias;
        float4 c = s4[tid];
        #pragma unroll
        for (int jb = 0; jb < 25; jb++){
            float4 n = s4[tid + jb + 1];
            float w0_ = sw[4*jb+0], w1_ = sw[4*jb+1], w2_ = sw[4*jb+2], w3_ = sw[4*jb+3];
            a0 += w0_*c.x; a1 += w0_*c.y; a2 += w0_*c.z; a3 += w0_*c.w;
            a0 += w1_*c.y; a1 += w1_*c.z; a2 += w1_*c.w; a3 += w1_*n.x;
            a0 += w2_*c.z; a1 += w2_*c.w; a2 += w2_*n.x; a3 += w2_*n.y;
            a0 += w3_*c.w; a1 += w3_*n.x; a2 += w3_*n.y; a3 += w3_*n.z;   // sw[99]=0
            c = n;
        }
        int hp = t0 + tid*4;
        if (hp     < p1){ int b = bin_of(a0); atomicAdd(&hist[b>>1], 1u << ((b&1)*16)); }
        if (hp + 1 < p1){ int b = bin_of(a1); atomicAdd(&hist[b>>1], 1u << ((b&1)*16)); }
        if (hp + 2 < p1){ int b = bin_of(a2); atomicAdd(&hist[b>>1], 1u << ((b&1)*16)); }
        if (hp + 3 < p1){ int b = bin_of(a3); atomicAdd(&hist[b>>1], 1u << ((b&1)*16)); }
        __syncthreads();
    }
    u32* Hc = H + (size_t)colv * NB;
    for (int i = tid; i < NB/2; i += 512){
        u32 w = hist[i];
        if (w){
            u32 lo = w & 0xFFFFu, hi = w >> 16;
            if (lo) atomicAdd(&Hc[2*i],   lo);
            if (hi) atomicAdd(&Hc[2*i+1], hi);
        }
    }
}

// ---------------- K=9 conv+hist: float4 shifted window, 4 outputs/thread ----------------
#define C9CHUNK 8192             // 4 tiles of 2048 per block
template<int FOLDIN>
__global__ __launch_bounds__(512) void conv9_lds(
    const float* __restrict__ In, u32* __restrict__ H,
    const float* __restrict__ Wt, const float* __restrict__ Bs,
    int Hin, int Hout, int Wi, int Wo, float bscale)
{
    __shared__ u32 hist[NB/2];                 // 24 KB
    __shared__ __align__(16) float s0f[2056];  // window: logical float i = h - (t0-8), i in [0,2056)
    __shared__ __align__(16) float s1f[2056];
    const int colv = blockIdx.y;               // o*Wo + wp
    const int o = colv / Wo, wp = colv % Wo;
    const int tid = threadIdx.x;
    const int lane = tid & 63;
    const int p0 = blockIdx.x * C9CHUNK;
    const int p1 = min(p0 + C9CHUNK, Hout);
    if (p0 >= Hout) return;
    for (int i = tid; i < NB/2; i += 512) hist[i] = 0;
    float w0r[9], w1r[9];
    #pragma unroll
    for (int j = 0; j < 9; j++){ w0r[j] = Wt[(o*2)*9 + j]; w1r[j] = Wt[(o*2)*9 + 9 + j]; }
    const float bv = bscale * Bs[o];
    __syncthreads();
    const float* i00 = In + (size_t)(0*Wi + (FOLDIN ? 2*wp   : wp))*STRIDE;
    const float* i01 = In + (size_t)(0*Wi + (FOLDIN ? 2*wp+1 : wp))*STRIDE;
    const float* i10 = In + (size_t)(1*Wi + (FOLDIN ? 2*wp   : wp))*STRIDE;
    const float* i11 = In + (size_t)(1*Wi + (FOLDIN ? 2*wp+1 : wp))*STRIDE;
    const float4* s40 = (const float4*)s0f;
    const float4* s41 = (const float4*)s1f;
    for (int t0 = p0; t0 < p1; t0 += 2048){
        for (int i = tid; i < 2056; i += 512){
            int h = t0 - 8 + i;
            float v0 = 0.f, v1 = 0.f;
            if (h >= 0 && h < Hin){
                v0 = FOLDIN ? (i00[h] + i01[h]) : i00[h];
                v1 = FOLDIN ? (i10[h] + i11[h]) : i10[h];
            }
            s0f[i] = v0; s1f[i] = v1;
        }
        __syncthreads();
        // outputs hp = t0 + 4*tid + r (r=0..3); tap j reads logical float 4*tid + r + j
        float a0 = bv, a1 = bv, a2 = bv, a3 = bv;
        {   // channel 0 taps j=0..8 ascending (preserve original accumulation order)
            float4 X = s40[tid], Y = s40[tid+1], Z = s40[tid+2];
            a0 += w0r[0]*X.x; a1 += w0r[0]*X.y; a2 += w0r[0]*X.z; a3 += w0r[0]*X.w;
            a0 += w0r[1]*X.y; a1 += w0r[1]*X.z; a2 += w0r[1]*X.w; a3 += w0r[1]*Y.x;
            a0 += w0r[2]*X.z; a1 += w0r[2]*X.w; a2 += w0r[2]*Y.x; a3 += w0r[2]*Y.y;
            a0 += w0r[3]*X.w; a1 += w0r[3]*Y.x; a2 += w0r[3]*Y.y; a3 += w0r[3]*Y.z;
            a0 += w0r[4]*Y.x; a1 += w0r[4]*Y.y; a2 += w0r[4]*Y.z; a3 += w0r[4]*Y.w;
            a0 += w0r[5]*Y.y; a1 += w0r[5]*Y.z; a2 += w0r[5]*Y.w; a3 += w0r[5]*Z.x;
            a0 += w0r[6]*Y.z; a1 += w0r[6]*Y.w; a2 += w0r[6]*Z.x; a3 += w0r[6]*Z.y;
            a0 += w0r[7]*Y.w; a1 += w0r[7]*Z.x; a2 += w0r[7]*Z.y; a3 += w0r[7]*Z.z;
            a0 += w0r[8]*Z.x; a1 += w0r[8]*Z.y; a2 += w0r[8]*Z.z; a3 += w0r[8]*Z.w;
        }
        {   // then channel 1
            float4 X = s41[tid], Y = s41[tid+1], Z = s41[tid+2];
            a0 += w1r[0]*X.x; a1 += w1r[0]*X.y; a2 += w1r[0]*X.z; a3 += w1r[0]*X.w;
            a0 += w1r[1]*X.y; a1 += w1r[1]*X.z; a2 += w1r[1]*X.w; a3 += w1r[1]*Y.x;
            a0 += w1r[2]*X.z; a1 += w1r[2]*X.w; a2 += w1r[2]*Y.x; a3 += w1r[2]*Y.y;
            a0 += w1r[3]*X.w; a1 += w1r[3]*Y.x; a2 += w1r[3]*Y.y; a3 += w1r[3]*Y.z;
            a0 += w1r[4]*Y.x; a1 += w1r[4]*Y.y; a2 += w1r[4]*Y.z; a3 += w1r[4]*Y.w;
            a0 += w1r[5]*Y.y; a1 += w1r[5]*Y.z; a2 += w1r[5]*Y.w; a3 += w1r[5]*Z.x;
            a0 += w1r[6]*Y.z; a1 += w1r[6]*Y.w; a2 += w1r[6]*Z.x; a3 += w1r[6]*Z.y;
            a0 += w1r[7]*Y.w; a1 += w1r[7]*Z.x; a2 += w1r[7]*Z.y; a3 += w1r[7]*Z.z;
            a0 += w1r[8]*Z.x; a1 += w1r[8]*Z.y; a2 += w1r[8]*Z.z; a3 += w1r[8]*Z.w;
        }
        int hp = t0 + tid*4;
        lds_hist_dedup(hist, bin_of(a0), hp     < p1, lane);
        lds_hist_dedup(hist, bin_of(a1), hp + 1 < p1, lane);
        lds_hist_dedup(hist, bin_of(a2), hp + 2 < p1, lane);
        lds_hist_dedup(hist, bin_of(a3), hp + 3 < p1, lane);
        __syncthreads();
    }
    u32* Hc = H + (size_t)colv * NB;
    for (int i = tid; i < NB/2; i += 512){
        u32 w = hist[i];
        if (w){
            u32 lo = w & 0xFFFFu, hi = w >> 16;
            if (lo) atomicAdd(&Hc[2*i],   lo);
            if (hi) atomicAdd(&Hc[2*i+1], hi);
        }
    }
}

// ---------------- layer-19 conv+hist (K=358, 2->5ch; global dedup atomics) ----------------
template<int INC, int OUTC>
__global__ __launch_bounds__(256) void conv_hist_t(
    const float* __restrict__ In, u32* __restrict__ H,
    const float* __restrict__ Wt, const float* __restrict__ Bs,
    int Hin, int Hout, int K, int pad, int Wi, int Wo, int foldIn, float bscale)
{
    __shared__ float sIn[INC][613];
    __shared__ float sW[OUTC*INC*358];
    const int wp = blockIdx.y;
    const int h0 = blockIdx.x * 256;
    const int tid = threadIdx.x;
    const int lane = tid & 63;
    const int tl = 256 + K - 1;
    for (int t = tid; t < INC*tl; t += 256){
        int c = t / tl, r = t - c*tl;
        int h = h0 - pad + r;
        float v = 0.f;
        if (h >= 0 && h < Hin){
            if (foldIn) v = In[(size_t)(c*Wi + 2*wp)*STRIDE + h] + In[(size_t)(c*Wi + 2*wp + 1)*STRIDE + h];
            else        v = In[(size_t)(c*Wi + wp)*STRIDE + h];
        }
        sIn[c][r] = v;
    }
    for (int t = tid; t < OUTC*INC*K; t += 256) sW[t] = Wt[t];
    __syncthreads();
    int hp = h0 + tid;
    bool valid = (hp < Hout);
    float acc[OUTC];
    #pragma unroll
    for (int o = 0; o < OUTC; o++) acc[o] = bscale * Bs[o];
    for (int c = 0; c < INC; c++){
        for (int j = 0; j < K; j++){
            float xv = sIn[c][tid + j];
            #pragma unroll
            for (int o = 0; o < OUTC; o++) acc[o] += sW[(o*INC + c)*K + j] * xv;
        }
    }
    #pragma unroll
    for (int o = 0; o < OUTC; o++)
        hist_add(H + (size_t)(o*Wo + wp)*NB, bin_of(acc[o]), valid, lane);
}

// ---------------- fused scan + reconstruct (binary search PER RUN) + next-bin zeroing ----------------
__global__ __launch_bounds__(1024) void scan_fill(
    const u32* __restrict__ H, float* __restrict__ dst, const float* __restrict__ alphaPtr,
    int kOut, int dup, int act, uint4* __restrict__ zb)
{
    __shared__ u32 pre[NB];          // 48 KB inclusive prefix
    __shared__ u32 warr[16];
    const int col = blockIdx.y;
    const int tid = threadIdx.x;
    const int lane = tid & 63, wv = tid >> 6;
    const u32* Hc = H + (size_t)col * NB;
    for (int i = tid; i < NB; i += 1024) pre[i] = Hc[i];
    __syncthreads();
    const int base = tid * 12;
    u32 v[12]; u32 s = 0;
    #pragma unroll
    for (int i = 0; i < 12; i++){ v[i] = pre[base + i]; s += v[i]; v[i] = s; }
    u32 ss = s;
    #pragma unroll
    for (int d = 1; d < 64; d <<= 1){
        u32 t = __shfl_up(ss, d);
        if (lane >= d) ss += t;
    }
    if (lane == 63) warr[wv] = ss;
    __syncthreads();
    u32 wb = 0;
    #pragma unroll
    for (int w = 0; w < 16; w++) wb += (w < wv) ? warr[w] : 0u;
    u32 excl = wb + ss - s;
    #pragma unroll
    for (int i = 0; i < 12; i++) pre[base + i] = v[i] + excl;
    __syncthreads();

    const int S  = gridDim.x;
    const int nr = kOut / dup;
    const int per = (nr + S*1024 - 1) / (S*1024);
    int i = (blockIdx.x*1024 + tid) * per;
    const int i1 = min(i + per, nr);
    float* d = dst + (size_t)col * STRIDE;
    const float alpha = alphaPtr[0];
    int lo0 = 0;                                  // monotone lower bound across runs
    while (i < i1){
        int lo = lo0, hi = NB - 1;                // smallest bin with pre[bin] > i
        while (lo < hi){ int m = (lo + hi) >> 1; if (pre[m] > (u32)i) hi = m; else lo = m + 1; }
        float vv = bin_val(lo);
        if (act == ACT_PRELU)      vv = (vv >= 0.f) ? vv : alpha * vv;
        else if (act == ACT_RELU)  vv = (vv > 0.f) ? vv : 0.f;
        else                       vv = (vv > 0.f) ? vv : expm1f(vv);
        int e = (int)min((u32)i1, pre[lo]);
        for (; i < e; i++){
            int bse = i * dup;
            for (int dd = 0; dd < dup; dd++) d[bse + dd] = vv;
        }
        lo0 = lo + 1;                             // next rank's bin is strictly above lo
    }
    // zero the other bin buffer for the next layer (vectorized)
    const uint4 z = make_uint4(0,0,0,0);
    int lin = (blockIdx.y * gridDim.x + blockIdx.x) * 1024 + tid;
    int tot = gridDim.x * gridDim.y * 1024;
    for (int q = lin; q < ZW/4; q += tot) zb[q] = z;
}

// ---------------- FC: 1000 logits, one block each; then log_softmax ----------------
__global__ __launch_bounds__(256) void fc_dot(const float* __restrict__ A, const float* __restrict__ Wfc,
                                              const float* __restrict__ bfc, float* __restrict__ logits)
{
    const int t = blockIdx.x;            // 0..999
    const int o = t / 200, j = t - o*200;
    const float* wrow = Wfc + (size_t)j*1600;
    float acc = 0.f;
    for (int q = threadIdx.x; q < 1600; q += 256){
        int p = q >> 1, wq = q & 1;
        acc += wrow[q] * A[(size_t)(o*2 + wq)*STRIDE + p];
    }
    __shared__ float red[256];
    red[threadIdx.x] = acc;
    __syncthreads();
    for (int s = 128; s > 0; s >>= 1){
        if (threadIdx.x < s) red[threadIdx.x] += red[threadIdx.x + s];
        __syncthreads();
    }
    if (threadIdx.x == 0) logits[t] = red[0] + bfc[j];
}

__global__ __launch_bounds__(1024) void lsm(const float* __restrict__ logits, float* __restrict__ out)
{
    const int tid = threadIdx.x;
    __shared__ float red[1024];
    float lg = (tid < 1000) ? logits[tid] : -INFINITY;
    red[tid] = lg;
    __syncthreads();
    for (int s = 512; s > 0; s >>= 1){
        if (tid < s) red[tid] = fmaxf(red[tid], red[tid + s]);
        __syncthreads();
    }
    float m = red[0];
    __syncthreads();
    red[tid] = (tid < 1000) ? expf(lg - m) : 0.f;
    __syncthreads();
    for (int s = 512; s > 0; s >>= 1){
        if (tid < s) red[tid] += red[tid + s];
        __syncthreads();
    }
    float lse = logf(red[0]);
    if (tid < 1000) out[tid] = lg - m - lse;
}

extern "C" void kernel_launch(void* const* d_in, const int* in_sizes, int n_in,
                              void* d_out, int out_size, void* d_ws, size_t ws_size,
                              hipStream_t stream)
{
    (void)in_sizes; (void)n_in; (void)out_size;
    const size_t need = (size_t)24*STRIDE*4 + (size_t)2*ZW*4 + 4096;
    if (ws_size < need) return;

    const float* x   = (const float*)d_in[0];
    const float* w0  = (const float*)d_in[1];
    const float* b0  = (const float*)d_in[2];
    const float* wm  = (const float*)d_in[3];
    const float* bm  = (const float*)d_in[4];
    const float* w18 = (const float*)d_in[5];
    const float* b18 = (const float*)d_in[6];
    const float* w19 = (const float*)d_in[7];
    const float* b19 = (const float*)d_in[8];
    const float* a1  = (const float*)d_in[9];
    const float* a2  = (const float*)d_in[10];
    const float* Wfc = (const float*)d_in[11];
    const float* bfc = (const float*)d_in[12];

    float* b1   = (float*)d_ws;
    float* fx   = b1 + (size_t)16*STRIDE;
    u32*  bin0  = (u32*)(fx + (size_t)8*STRIDE);
    u32*  bin1  = bin0 + (size_t)ZW;
    float* logits = (float*)(bin1 + (size_t)ZW);

    u32* cur = bin0;
    u32* nxt = bin1;

    // fold+transpose x; zero bin0
    foldx<<<1024, 256, 0, stream>>>(x, fx, (uint4*)cur);

    // ---- layer 0: conv(99, pad 98) -> fold(x2 dup) -> kmax 262144 -> PReLU(a1) ----
    conv0_lds<<<dim3(33, 16), 512, 0, stream>>>(fx, cur, w0, b0);
    scan_fill<<<dim3(16, 16), 1024, 0, stream>>>(cur, b1, a1, 262144, 2, ACT_PRELU, (uint4*)nxt);
    { u32* t = cur; cur = nxt; nxt = t; }
    int Hin = 262144;

    // ---- layers 1..17: conv(9, pad 8) -> kmax -> PReLU(a2)/ReLU ----
    static const int ks[17] = {249036,235929,222822,209715,196608,183500,170393,157286,
                               144179,131072,117964,104857,91750,78643,65536,52428,39321};
    for (int i = 0; i < 17; i++){
        int Hout = Hin + 8;
        int nch = (Hout + C9CHUNK - 1) / C9CHUNK;
        conv9_lds<0><<<dim3(nch, 16), 512, 0, stream>>>(
            b1, cur, wm + (size_t)i*36, bm + (size_t)i*2, Hin, Hout, 8, 8, 1.f);
        scan_fill<<<dim3(16, 16), 1024, 0, stream>>>(cur, b1, a2, ks[i], 1,
                                                     (i == 0) ? ACT_PRELU : ACT_RELU, (uint4*)nxt);
        { u32* t = cur; cur = nxt; nxt = t; }
        Hin = ks[i];
    }

    // ---- layer 18: conv(9) -> fold(widths 8->4, x2 dup) -> kmax 26214 -> ELU ----
    {
        int Hout = Hin + 8;   // 39329
        int nch = (Hout + C9CHUNK - 1) / C9CHUNK;
        conv9_lds<1><<<dim3(nch, 8), 512, 0, stream>>>(
            b1, cur, w18, b18, Hin, Hout, 8, 4, 2.f);
        scan_fill<<<dim3(4, 8), 1024, 0, stream>>>(cur, b1, a2, 26214, 2, ACT_ELU, (uint4*)nxt);
        { u32* t = cur; cur = nxt; nxt = t; }
        Hin = 26214;
    }

    // ---- layer 19: conv(358, pad 357, 2->5ch) -> fold(widths 4->2, x5 dup) -> kmax 800 -> ELU ----
    {
        int Hout = Hin + 714 - 358 + 1;   // 26571
        conv_hist_t<2,5><<<dim3((Hout + 255)/256, 2), 256, 0, stream>>>(
            b1, cur, w19, b19, Hin, Hout, 358, 357, 4, 2, 1, 2.f);
        scan_fill<<<dim3(1, 10), 1024, 0, stream>>>(cur, b1, a2, 800, 5, ACT_ELU, (uint4*)nxt);
    }

    // ---- FC + log_softmax ----
    fc_dot<<<1000, 256, 0, stream>>>(b1, Wfc, bfc, logits);
    lsm<<<1, 1024, 0, stream>>>(logits, (float*)d_out);
}